// Round 10
// baseline (637.610 us; speedup 1.0000x reference)
//
#include <hip/hip_runtime.h>
#include <stdint.h>

#define V_N    4096
#define NNZ_N  36864
#define S_N    216        // X*Y*Z = 6*6*6
#define ST_TOT 27         // S_N / 8
#define PLANES 256        // K * FIN
#define BPLANES 224       // basis planes per stl (k=1..7)

typedef float  f32x2 __attribute__((ext_vector_type(2)));
typedef float  f32x4 __attribute__((ext_vector_type(4)));
typedef short  s16x4 __attribute__((ext_vector_type(4)));
typedef short  s16x8 __attribute__((ext_vector_type(8)));

static __device__ __forceinline__ unsigned short f2bf(float f){
    union { float f; unsigned u; } x; x.f = f;
    unsigned r = x.u + 0x7FFFu + ((x.u >> 16) & 1u);   // round-to-nearest-even
    return (unsigned short)(r >> 16);
}
static __device__ __forceinline__ unsigned packbf(float lo, float hi){
    unsigned r;
    asm("v_cvt_pk_bf16_f32 %0, %1, %2" : "=v"(r) : "v"(lo), "v"(hi));
    return r;
}
static __device__ __forceinline__ void pkfma(f32x2& acc, f32x2 c, f32x2 vv){
    asm("v_pk_fma_f32 %0, %1, %2, %0" : "+v"(acc) : "v"(c), "v"(vv));
}
#define BLO(u) __uint_as_float((u) << 16)
#define BHI(u) __uint_as_float((u) & 0xFFFF0000u)

// tr_b16-staging permutation (verified r7/r9)
static __device__ __forceinline__ int bperm(int p, int vrr){
    return ((vrr >> 2) << 10) + (((vrr >> 1) & 1) << 9)
         + ((p >> 5) << 6) + (((p >> 2) & 1) << 5) + (((p >> 3) & 3) << 3)
         + ((p & 3) << 1) + (vrr & 1);
}

// ---------------- k_prep: fused hist + degree-sort + group offsets (1 block) --------
__global__ __launch_bounds__(1024) void k_prep(
    const int* __restrict__ rows, int* __restrict__ row_order,
    int* __restrict__ sp, int* __restrict__ gcnt, int* __restrict__ goff,
    int* __restrict__ rcur)
{
    __shared__ int cnt[4096];
    __shared__ int c2[4096];
    __shared__ int dh[64];
    int t = threadIdx.x;
    #pragma unroll
    for (int i = 0; i < 4; ++i) cnt[t + i*1024] = 0;
    if (t < 64) dh[t] = 0;
    __syncthreads();
    for (int e = t; e < NNZ_N; e += 1024) atomicAdd(&cnt[rows[e]], 1);
    __syncthreads();
    #pragma unroll
    for (int i = 0; i < 4; ++i){
        int d = cnt[t + i*1024]; if (d > 63) d = 63;
        atomicAdd(&dh[d], 1);
    }
    __syncthreads();
    if (t == 0){ int s = 0; for (int i = 0; i < 64; ++i){ int x = dh[i]; dh[i] = s; s += x; } }
    __syncthreads();
    #pragma unroll
    for (int i = 0; i < 4; ++i){
        int v = t + i*1024;
        int d = cnt[v]; int db = d > 63 ? 63 : d;
        int pos = atomicAdd(&dh[db], 1);
        row_order[pos] = v; sp[v] = pos; c2[pos] = d;
    }
    #pragma unroll
    for (int i = 0; i < 4; ++i) rcur[t + i*1024] = 0;
    __syncthreads();
    if (t == 0){
        int off = 0;
        for (int g = 0; g < 64; ++g){
            int d = c2[g*64 + 63]; if (d > 64) d = 64;
            gcnt[g] = d; goff[g] = off; off += (d + 3) * 64;
        }
    }
}

// ---------------- k_fill2: ELL fill (blocks 0..143) + W pack (blocks 144..175) ------
__global__ void k_fill2(const int* __restrict__ rows, const int* __restrict__ cols,
                        const float* __restrict__ vals, const int* __restrict__ sp,
                        const int* __restrict__ gcnt, const int* __restrict__ goff,
                        int* __restrict__ rcur, unsigned* __restrict__ ell,
                        const float* __restrict__ w, unsigned short* __restrict__ wtab)
{
    int bid = blockIdx.x, t = threadIdx.x;
    if (bid < 144){
        int e = bid * 256 + t;
        if (e < NNZ_N){
            int r = rows[e]; int s = sp[r]; int g = s >> 6; int l = s & 63;
            int i = atomicAdd(&rcur[r], 1);
            if (i < gcnt[g])
                ell[goff[g] + i * 64 + l] =
                    ((unsigned)cols[e] << 4) | ((unsigned)f2bf(vals[e]) << 16);
        }
    } else {
        int idx = (bid - 144) * 256 + t;   // 0..8191
        int slot = idx >> 3, j = idx & 7;
        int ki = slot >> 7, nh = (slot >> 6) & 1, l = slot & 63;
        int p  = ki * 32 + ((l >> 4) << 3) + j;
        int fo = nh * 16 + (l & 15);
        wtab[idx] = f2bf(w[p * 32 + fo]);
    }
}

// ---------------- k_pre: input transpose -> t0 tiles (bf16) ----------------
// t0t layout: t0t[(st*512 + vb)*256 + f*8 + vrr]  (4 KB contiguous per (st,vb) tile)
__global__ __launch_bounds__(256, 4) void k_pre(
    const float* __restrict__ in, uint4* __restrict__ t0t)
{
    __shared__ unsigned short lds[64 * 218];   // 27.3 KB, row stride 436 B
    int bid = blockIdx.x;
    int f = bid >> 6, vblk = bid & 63;
    int t = threadIdx.x;
    const f32x4* src = (const f32x4*)(in + ((size_t)f * V_N + vblk * 64) * S_N);

    #pragma unroll
    for (int it = 0; it < 14; ++it){
        int idx = t + it * 256;                 // float4 index, 0..3455
        if (idx < 3456){
            int vloc = (int)(((unsigned)idx * 4855u) >> 18);   // idx / 54
            int s4   = idx - vloc * 54;
            f32x4 a = __builtin_nontemporal_load(&src[idx]);
            uint2 q; q.x = packbf(a.x, a.y); q.y = packbf(a.z, a.w);
            *(uint2*)((char*)lds + vloc * 436 + s4 * 8) = q;
        }
    }
    __syncthreads();
    #pragma unroll
    for (int it = 0; it < 7; ++it){
        int idx = t + it * 256;
        if (idx < ST_TOT * 64){
            int stl = idx >> 6, vl = idx & 63;
            uint4 q = *(const uint4*)((const char*)lds + vl * 436 + stl * 16);
            t0t[((size_t)(stl * 512 + vblk * 8 + (vl >> 3))) * 256 + f * 8 + (vl & 7)] = q;
        }
    }
}

// ---------------- Phase A: LDS-resident Chebyshev recurrence ----------------
// basis3 (chunk-local): basis3[(stl*512 + vb)*1792 + ((k-1)*32+f)*8 + vrr]
__global__ __launch_bounds__(1024, 8) void k_phaseA(
    const int* __restrict__ row_order,
    const int* __restrict__ goff, const int* __restrict__ gcnt,
    const unsigned* __restrict__ ell, const uint4* __restrict__ t0t,
    uint4* __restrict__ basis3, int st0)
{
    __shared__ uint4 T4[V_N];        // 64 KB
    int f   = blockIdx.x & 31;
    int stl = blockIdx.x >> 5;       // chunk-local
    int st_g = st0 + stl;            // global
    int t = threadIdx.x;

    // T0 from t0t (8x128 B chunks per wave-instr)
    const uint4* t0p = t0t + ((size_t)st_g << 9) * 256 + f * 8;
    #pragma unroll
    for (int rr = 0; rr < 4; ++rr){
        int v = t + rr * 1024;
        T4[v] = t0p[(size_t)(v >> 3) * 256 + (v & 7)];
    }
    __syncthreads();

    // wave w owns groups {w, w+16, w+32, w+48}  (strided => balanced degrees)
    int w = t >> 6, lane = t & 63;
    int vr[4], gba[4], gcn[4];
    #pragma unroll
    for (int rr = 0; rr < 4; ++rr){
        int g = w + rr * 16;
        vr[rr]  = row_order[g * 64 + lane];
        gba[rr] = goff[g] + lane;
        gcn[rr] = __builtin_amdgcn_readfirstlane(gcnt[g]);
    }
    uint4 tm2[4];
    #pragma unroll
    for (int rr = 0; rr < 4; ++rr) tm2[rr] = T4[vr[rr]];   // T0 own rows

    for (int k = 1; k < 8; ++k){
        uint4 nst[4];
        #pragma unroll
        for (int rr = 0; rr < 4; ++rr){
            f32x2 ac0 = {0,0}, ac1 = {0,0}, ac2 = {0,0}, ac3 = {0,0};
            const unsigned* ep = ell + gba[rr];
            int cnt = gcn[rr];
            unsigned u0 = ep[0];
            unsigned u1 = ep[64];
            for (int i = 0; i < cnt; i += 2){
                unsigned n0 = ep[(i + 2) << 6];     // prefetch next pair (pad rows are 0)
                unsigned n1 = ep[(i + 3) << 6];
                uint4 q0 = *(const uint4*)((const char*)T4 + (u0 & 0xFFF0u));
                uint4 q1 = *(const uint4*)((const char*)T4 + (u1 & 0xFFF0u));
                float v0 = __uint_as_float(u0 & 0xFFFF0000u);
                float v1 = __uint_as_float(u1 & 0xFFFF0000u);
                f32x2 vv0 = {v0, v0};
                f32x2 vv1 = {v1, v1};
                f32x2 c;
                c.x = BLO(q0.x); c.y = BHI(q0.x);  pkfma(ac0, c, vv0);
                c.x = BLO(q0.y); c.y = BHI(q0.y);  pkfma(ac1, c, vv0);
                c.x = BLO(q0.z); c.y = BHI(q0.z);  pkfma(ac2, c, vv0);
                c.x = BLO(q0.w); c.y = BHI(q0.w);  pkfma(ac3, c, vv0);
                c.x = BLO(q1.x); c.y = BHI(q1.x);  pkfma(ac0, c, vv1);
                c.x = BLO(q1.y); c.y = BHI(q1.y);  pkfma(ac1, c, vv1);
                c.x = BLO(q1.z); c.y = BHI(q1.z);  pkfma(ac2, c, vv1);
                c.x = BLO(q1.w); c.y = BHI(q1.w);  pkfma(ac3, c, vv1);
                u0 = n0; u1 = n1;
            }
            float a0 = ac0.x, a1 = ac0.y, a2 = ac1.x, a3 = ac1.y;
            float a4 = ac2.x, a5 = ac2.y, a6 = ac3.x, a7 = ac3.y;
            if (k > 1){
                a0 = fmaf(2.f, a0, -BLO(tm2[rr].x));  a1 = fmaf(2.f, a1, -BHI(tm2[rr].x));
                a2 = fmaf(2.f, a2, -BLO(tm2[rr].y));  a3 = fmaf(2.f, a3, -BHI(tm2[rr].y));
                a4 = fmaf(2.f, a4, -BLO(tm2[rr].z));  a5 = fmaf(2.f, a5, -BHI(tm2[rr].z));
                a6 = fmaf(2.f, a6, -BLO(tm2[rr].w));  a7 = fmaf(2.f, a7, -BHI(tm2[rr].w));
            }
            nst[rr].x = packbf(a0, a1); nst[rr].y = packbf(a2, a3);
            nst[rr].z = packbf(a4, a5); nst[rr].w = packbf(a6, a7);
        }
        #pragma unroll
        for (int rr = 0; rr < 4; ++rr) tm2[rr] = T4[vr[rr]];   // T_{k-1} own rows
        __syncthreads();
        #pragma unroll
        for (int rr = 0; rr < 4; ++rr) T4[vr[rr]] = nst[rr];   // LDS <- T_k
        __syncthreads();
        // basis write of T_k from LDS: 8x128 B contiguous chunks per wave-instr
        uint4* bp = basis3 + ((size_t)stl << 9) * 1792 + ((k - 1) * 32 + f) * 8;
        #pragma unroll
        for (int rr = 0; rr < 4; ++rr){
            int v = t + rr * 1024;
            bp[(size_t)(v >> 3) * 1792 + (v & 7)] = T4[v];
        }
    }
}

// ---------------- Phase B: grid-stride pipelined projection GEMM ----------------
// per tile: stage regs->LDS (permuted), issue next tile's loads, MFMA, epilogue
__global__ __launch_bounds__(256, 3) void k_phaseB(
    const uint4* __restrict__ basis3, const uint4* __restrict__ t0t,
    const uint4* __restrict__ wtab, const float* __restrict__ bias,
    float* __restrict__ out, int st0, int ntiles)
{
    __shared__ uint4 A[2048];      // 32 KB; outT overlays A in epilogue
    __shared__ uint4 WL[1024];     // 16 KB W
    int t = threadIdx.x;
    int lane = t & 63, w = t >> 6;

    // one-time W stage (contiguous)
    #pragma unroll
    for (int it = 0; it < 4; ++it) WL[(it << 8) + t] = wtab[(it << 8) + t];

    auto LOAD = [&](int tile, uint4* q){
        int stl = tile >> 9, vb = tile & 511;
        const uint4* srcT = t0t + ((size_t)((st0 + stl) * 512 + vb)) * 256;
        const uint4* srcB = basis3 + ((size_t)(stl * 512 + vb)) * 1792;
        q[0] = srcT[t];
        #pragma unroll
        for (int it = 0; it < 7; ++it) q[1 + it] = srcB[it * 256 + t];
    };

    int tile = blockIdx.x;
    uint4 q[8];
    uint4 q0;
    {
        uint4 tmp[8]; LOAD(tile, tmp);
        q0 = tmp[0];
        #pragma unroll
        for (int i = 0; i < 7; ++i) q[i] = tmp[1 + i];
        q[7] = tmp[0];   // placeholder; real q0 kept separately
    }

    int p0 = t >> 3, vr0 = t & 7;
    int b0 = bperm(p0, vr0);
    int bb[7];
    #pragma unroll
    for (int it = 0; it < 7; ++it){
        int g = it * 256 + t;
        bb[it] = bperm(32 + (g >> 3), g & 7);
    }
    unsigned abase = (unsigned)(size_t)(&A[0]) + ((w >> 1) << 14) + ((w & 1) << 13) + (lane << 3);
    const char* wbase = (const char*)&WL[0];

    for (; tile < ntiles; tile += 2048){
        __syncthreads();                     // A free (prev epilogue reads done)
        // scatter staged regs into permuted LDS image
        A[b0] = q0;
        #pragma unroll
        for (int it = 0; it < 7; ++it) A[bb[it]] = q[it];
        // issue next tile's loads (fly under MFMA + epilogue)
        int nt = tile + 2048;
        if (nt < ntiles){
            int stl = nt >> 9, vb = nt & 511;
            const uint4* srcT = t0t + ((size_t)((st0 + stl) * 512 + vb)) * 256;
            const uint4* srcB = basis3 + ((size_t)(stl * 512 + vb)) * 1792;
            q0 = srcT[t];
            #pragma unroll
            for (int it = 0; it < 7; ++it) q[it] = srcB[it * 256 + t];
        }
        __syncthreads();                     // A image complete

        f32x4 acc0 = {0,0,0,0}, acc1 = {0,0,0,0};
        #pragma unroll
        for (int ki = 0; ki < 8; ++ki){
            s16x4 x0, x1;
            unsigned a0 = abase + (ki << 10);
            asm volatile("ds_read_b64_tr_b16 %0, %2\n\t"
                         "ds_read_b64_tr_b16 %1, %2 offset:512\n\t"
                         "s_waitcnt lgkmcnt(0)"
                         : "=&v"(x0), "=&v"(x1) : "v"(a0));
            __builtin_amdgcn_sched_barrier(0);
            s16x8 af;
            af[0]=x0[0]; af[1]=x0[1]; af[2]=x0[2]; af[3]=x0[3];
            af[4]=x1[0]; af[5]=x1[1]; af[6]=x1[2]; af[7]=x1[3];
            s16x8 bf0 = *(const s16x8*)(wbase + ((((ki * 2 + 0) << 6) + lane) << 4));
            s16x8 bf1 = *(const s16x8*)(wbase + ((((ki * 2 + 1) << 6) + lane) << 4));
            acc0 = __builtin_amdgcn_mfma_f32_16x16x32_bf16(af, bf0, acc0, 0, 0, 0);
            acc1 = __builtin_amdgcn_mfma_f32_16x16x32_bf16(af, bf1, acc1, 0, 0, 0);
        }

        __syncthreads();                     // all tr-reads of A done
        float* outT = (float*)&A[0];         // [fo][68] floats (8.7 KB)
        {
            int rl0 = w * 16 + ((lane >> 4) << 2);
            int foA = lane & 15, foB = 16 + (lane & 15);
            float2 p;
            p.x = acc0[0]; p.y = acc0[1]; *(float2*)&outT[foA*68 + rl0]     = p;
            p.x = acc0[2]; p.y = acc0[3]; *(float2*)&outT[foA*68 + rl0 + 2] = p;
            p.x = acc1[0]; p.y = acc1[1]; *(float2*)&outT[foB*68 + rl0]     = p;
            p.x = acc1[2]; p.y = acc1[3]; *(float2*)&outT[foB*68 + rl0 + 2] = p;
        }
        __syncthreads();                     // outT complete
        {
            int stl = tile >> 9, vb = tile & 511;
            int fo = t >> 3;
            int rl = (t & 7) << 3;           // 8 rows = 1 v, all 8 sl
            float bs = bias[fo];
            float2 r0 = *(const float2*)&outT[fo*68 + rl];
            float2 r1 = *(const float2*)&outT[fo*68 + rl + 2];
            float2 r2 = *(const float2*)&outT[fo*68 + rl + 4];
            float2 r3 = *(const float2*)&outT[fo*68 + rl + 6];
            int v = vb * 8 + (t & 7);
            float* gb = out + ((size_t)fo * V_N + v) * S_N + (st0 + stl) * 8;
            f32x4 o;
            o.x = r0.x + bs; o.y = r0.y + bs; o.z = r1.x + bs; o.w = r1.y + bs;
            __builtin_nontemporal_store(o, (f32x4*)gb);
            o.x = r2.x + bs; o.y = r2.y + bs; o.z = r3.x + bs; o.w = r3.y + bs;
            __builtin_nontemporal_store(o, (f32x4*)(gb + 4));
        }
    }
}

// ---------------- host ----------------
extern "C" void kernel_launch(void* const* d_in, const int* in_sizes, int n_in,
                              void* d_out, int out_size, void* d_ws, size_t ws_size,
                              hipStream_t stream)
{
    const float* inp  = (const float*)d_in[0];
    const float* wgt  = (const float*)d_in[1];
    const float* bias = (const float*)d_in[2];
    const float* vals = (const float*)d_in[3];
    const int*   rows = (const int*)d_in[4];
    const int*   cols = (const int*)d_in[5];
    float* out = (float*)d_out;

    char* ws = (char*)d_ws;
    size_t o = 0;
    auto alloc = [&](size_t bytes) -> void* {
        void* p = ws + o; o = (o + bytes + 255) & ~(size_t)255; return p;
    };
    const size_t ELL_B = (size_t)64 * 67 * 64 * 4;   // 1.05 MB hard cap
    int* row_order = (int*)alloc(4096 * 4);
    int* sp        = (int*)alloc(4096 * 4);
    int* gcnt      = (int*)alloc(64 * 4);
    int* goff      = (int*)alloc(64 * 4);
    int* rcur      = (int*)alloc(4096 * 4);
    unsigned* ell  = (unsigned*)alloc(ELL_B);
    uint4* wtab    = (uint4*)alloc(8192 * 2);
    uint4* t0buf   = (uint4*)alloc((size_t)ST_TOT * 512 * 256 * 16);   // 56.6 MB
    size_t used = o;

    size_t per_st = (size_t)512 * 1792 * 16;         // 14.68 MB per s8-tile
    size_t avail = (ws_size > used) ? (ws_size - used) : 0;
    int tiles_c = (int)(avail / per_st);
    if (tiles_c > 16) tiles_c = 16;                  // {16,11} chunk pattern
    if (tiles_c < 1) tiles_c = 1;
    uint4* basis = (uint4*)alloc(per_st * tiles_c);  // chunk-local, region-reused

    hipMemsetAsync(ell, 0, ELL_B, stream);
    k_prep  <<<1, 1024, 0, stream>>>(rows, row_order, sp, gcnt, goff, rcur);
    k_fill2 <<<176, 256, 0, stream>>>(rows, cols, vals, sp, gcnt, goff, rcur, ell,
                                      wgt, (unsigned short*)wtab);
    k_pre   <<<2048, 256, 0, stream>>>(inp, t0buf);

    for (int st0 = 0; st0 < ST_TOT; st0 += tiles_c){
        int tc = ST_TOT - st0; if (tc > tiles_c) tc = tiles_c;
        int ntiles = tc * 512;
        k_phaseA<<<32 * tc, 1024, 0, stream>>>(row_order, goff, gcnt, ell, t0buf, basis, st0);
        k_phaseB<<<2048, 256, 0, stream>>>(basis, t0buf, wtab, bias, out, st0, ntiles);
    }
}

// Round 11
// 447.833 us; speedup vs baseline: 1.4238x; 1.4238x over previous
//
#include <hip/hip_runtime.h>
#include <stdint.h>

#define V_N    4096
#define NNZ_N  36864
#define S_N    216        // X*Y*Z = 6*6*6
#define ST_TOT 27         // S_N / 8
#define PLANES 256        // K * FIN
#define BPLANES 224       // basis planes per stl (k=1..7)

typedef float  f32x2 __attribute__((ext_vector_type(2)));
typedef float  f32x4 __attribute__((ext_vector_type(4)));
typedef short  s16x4 __attribute__((ext_vector_type(4)));
typedef short  s16x8 __attribute__((ext_vector_type(8)));

static __device__ __forceinline__ unsigned short f2bf(float f){
    union { float f; unsigned u; } x; x.f = f;
    unsigned r = x.u + 0x7FFFu + ((x.u >> 16) & 1u);   // round-to-nearest-even
    return (unsigned short)(r >> 16);
}
static __device__ __forceinline__ unsigned packbf(float lo, float hi){
    unsigned r;
    asm("v_cvt_pk_bf16_f32 %0, %1, %2" : "=v"(r) : "v"(lo), "v"(hi));
    return r;
}
static __device__ __forceinline__ void pkfma(f32x2& acc, f32x2 c, f32x2 vv){
    asm("v_pk_fma_f32 %0, %1, %2, %0" : "+v"(acc) : "v"(c), "v"(vv));
}
#define BLO(u) __uint_as_float((u) << 16)
#define BHI(u) __uint_as_float((u) & 0xFFFF0000u)

// tr_b16-staging permutation for a 64-row subtile (verified r7/r9)
static __device__ __forceinline__ int bperm(int p, int vrr){
    return ((vrr >> 2) << 10) + (((vrr >> 1) & 1) << 9)
         + ((p >> 5) << 6) + (((p >> 2) & 1) << 5) + (((p >> 3) & 3) << 3)
         + ((p & 3) << 1) + (vrr & 1);
}

// ---------------- k_prep: fused hist + degree-sort + group offsets (1 block) --------
__global__ __launch_bounds__(1024) void k_prep(
    const int* __restrict__ rows, int* __restrict__ row_order,
    int* __restrict__ sp, int* __restrict__ gcnt, int* __restrict__ goff,
    int* __restrict__ rcur)
{
    __shared__ int cnt[4096];
    __shared__ int c2[4096];
    __shared__ int dh[64];
    int t = threadIdx.x;
    #pragma unroll
    for (int i = 0; i < 4; ++i) cnt[t + i*1024] = 0;
    if (t < 64) dh[t] = 0;
    __syncthreads();
    for (int e = t; e < NNZ_N; e += 1024) atomicAdd(&cnt[rows[e]], 1);
    __syncthreads();
    #pragma unroll
    for (int i = 0; i < 4; ++i){
        int d = cnt[t + i*1024]; if (d > 63) d = 63;
        atomicAdd(&dh[d], 1);
    }
    __syncthreads();
    if (t == 0){ int s = 0; for (int i = 0; i < 64; ++i){ int x = dh[i]; dh[i] = s; s += x; } }
    __syncthreads();
    #pragma unroll
    for (int i = 0; i < 4; ++i){
        int v = t + i*1024;
        int d = cnt[v]; int db = d > 63 ? 63 : d;
        int pos = atomicAdd(&dh[db], 1);
        row_order[pos] = v; sp[v] = pos; c2[pos] = d;
    }
    #pragma unroll
    for (int i = 0; i < 4; ++i) rcur[t + i*1024] = 0;
    __syncthreads();
    if (t == 0){
        int off = 0;
        for (int g = 0; g < 64; ++g){
            int d = c2[g*64 + 63]; if (d > 64) d = 64;
            gcnt[g] = d; goff[g] = off; off += (d + 3) * 64;
        }
    }
}

// ---------------- k_fill2: ELL fill (blocks 0..143) + W pack (blocks 144..175) ------
__global__ void k_fill2(const int* __restrict__ rows, const int* __restrict__ cols,
                        const float* __restrict__ vals, const int* __restrict__ sp,
                        const int* __restrict__ gcnt, const int* __restrict__ goff,
                        int* __restrict__ rcur, unsigned* __restrict__ ell,
                        const float* __restrict__ w, unsigned short* __restrict__ wtab)
{
    int bid = blockIdx.x, t = threadIdx.x;
    if (bid < 144){
        int e = bid * 256 + t;
        if (e < NNZ_N){
            int r = rows[e]; int s = sp[r]; int g = s >> 6; int l = s & 63;
            int i = atomicAdd(&rcur[r], 1);
            if (i < gcnt[g])
                ell[goff[g] + i * 64 + l] =
                    ((unsigned)cols[e] << 4) | ((unsigned)f2bf(vals[e]) << 16);
        }
    } else {
        int idx = (bid - 144) * 256 + t;   // 0..8191
        int slot = idx >> 3, j = idx & 7;
        int ki = slot >> 7, nh = (slot >> 6) & 1, l = slot & 63;
        int p  = ki * 32 + ((l >> 4) << 3) + j;
        int fo = nh * 16 + (l & 15);
        wtab[idx] = f2bf(w[p * 32 + fo]);
    }
}

// ---------------- k_pre: input transpose -> t0 tiles (bf16) ----------------
// t0t layout: t0t[(st*512 + vb)*256 + f*8 + vrr]  (4 KB contiguous per (st,vb) tile)
__global__ __launch_bounds__(256, 4) void k_pre(
    const float* __restrict__ in, uint4* __restrict__ t0t)
{
    __shared__ unsigned short lds[64 * 218];   // 27.3 KB, row stride 436 B
    int bid = blockIdx.x;
    int f = bid >> 6, vblk = bid & 63;
    int t = threadIdx.x;
    const f32x4* src = (const f32x4*)(in + ((size_t)f * V_N + vblk * 64) * S_N);

    #pragma unroll
    for (int it = 0; it < 14; ++it){
        int idx = t + it * 256;                 // float4 index, 0..3455
        if (idx < 3456){
            int vloc = (int)(((unsigned)idx * 4855u) >> 18);   // idx / 54
            int s4   = idx - vloc * 54;
            f32x4 a = __builtin_nontemporal_load(&src[idx]);
            uint2 q; q.x = packbf(a.x, a.y); q.y = packbf(a.z, a.w);
            *(uint2*)((char*)lds + vloc * 436 + s4 * 8) = q;
        }
    }
    __syncthreads();
    #pragma unroll
    for (int it = 0; it < 7; ++it){
        int idx = t + it * 256;
        if (idx < ST_TOT * 64){
            int stl = idx >> 6, vl = idx & 63;
            uint4 q = *(const uint4*)((const char*)lds + vl * 436 + stl * 16);
            t0t[((size_t)(stl * 512 + vblk * 8 + (vl >> 3))) * 256 + f * 8 + (vl & 7)] = q;
        }
    }
}

// ---------------- Phase A: LDS-resident Chebyshev recurrence ----------------
// basis3 (chunk-local): basis3[(stl*512 + vb)*1792 + ((k-1)*32+f)*8 + vrr]
__global__ __launch_bounds__(1024, 8) void k_phaseA(
    const int* __restrict__ row_order,
    const int* __restrict__ goff, const int* __restrict__ gcnt,
    const unsigned* __restrict__ ell, const uint4* __restrict__ t0t,
    uint4* __restrict__ basis3, int st0)
{
    __shared__ uint4 T4[V_N];        // 64 KB
    int f   = blockIdx.x & 31;
    int stl = blockIdx.x >> 5;       // chunk-local
    int st_g = st0 + stl;            // global
    int t = threadIdx.x;

    // T0 from t0t (8x128 B chunks per wave-instr)
    const uint4* t0p = t0t + ((size_t)st_g << 9) * 256 + f * 8;
    #pragma unroll
    for (int rr = 0; rr < 4; ++rr){
        int v = t + rr * 1024;
        T4[v] = t0p[(size_t)(v >> 3) * 256 + (v & 7)];
    }
    __syncthreads();

    // wave w owns groups {w, w+16, w+32, w+48}  (strided => balanced degrees)
    int w = t >> 6, lane = t & 63;
    int vr[4], gba[4], gcn[4];
    #pragma unroll
    for (int rr = 0; rr < 4; ++rr){
        int g = w + rr * 16;
        vr[rr]  = row_order[g * 64 + lane];
        gba[rr] = goff[g] + lane;
        gcn[rr] = __builtin_amdgcn_readfirstlane(gcnt[g]);
    }
    uint4 tm2[4];
    #pragma unroll
    for (int rr = 0; rr < 4; ++rr) tm2[rr] = T4[vr[rr]];   // T0 own rows

    for (int k = 1; k < 8; ++k){
        uint4 nst[4];
        #pragma unroll
        for (int rr = 0; rr < 4; ++rr){
            f32x2 ac0 = {0,0}, ac1 = {0,0}, ac2 = {0,0}, ac3 = {0,0};
            const unsigned* ep = ell + gba[rr];
            int cnt = gcn[rr];
            unsigned u0 = ep[0];
            unsigned u1 = ep[64];
            for (int i = 0; i < cnt; i += 2){
                unsigned n0 = ep[(i + 2) << 6];     // prefetch next pair (pad rows are 0)
                unsigned n1 = ep[(i + 3) << 6];
                uint4 q0 = *(const uint4*)((const char*)T4 + (u0 & 0xFFF0u));
                uint4 q1 = *(const uint4*)((const char*)T4 + (u1 & 0xFFF0u));
                float v0 = __uint_as_float(u0 & 0xFFFF0000u);
                float v1 = __uint_as_float(u1 & 0xFFFF0000u);
                f32x2 vv0 = {v0, v0};
                f32x2 vv1 = {v1, v1};
                f32x2 c;
                c.x = BLO(q0.x); c.y = BHI(q0.x);  pkfma(ac0, c, vv0);
                c.x = BLO(q0.y); c.y = BHI(q0.y);  pkfma(ac1, c, vv0);
                c.x = BLO(q0.z); c.y = BHI(q0.z);  pkfma(ac2, c, vv0);
                c.x = BLO(q0.w); c.y = BHI(q0.w);  pkfma(ac3, c, vv0);
                c.x = BLO(q1.x); c.y = BHI(q1.x);  pkfma(ac0, c, vv1);
                c.x = BLO(q1.y); c.y = BHI(q1.y);  pkfma(ac1, c, vv1);
                c.x = BLO(q1.z); c.y = BHI(q1.z);  pkfma(ac2, c, vv1);
                c.x = BLO(q1.w); c.y = BHI(q1.w);  pkfma(ac3, c, vv1);
                u0 = n0; u1 = n1;
            }
            float a0 = ac0.x, a1 = ac0.y, a2 = ac1.x, a3 = ac1.y;
            float a4 = ac2.x, a5 = ac2.y, a6 = ac3.x, a7 = ac3.y;
            if (k > 1){
                a0 = fmaf(2.f, a0, -BLO(tm2[rr].x));  a1 = fmaf(2.f, a1, -BHI(tm2[rr].x));
                a2 = fmaf(2.f, a2, -BLO(tm2[rr].y));  a3 = fmaf(2.f, a3, -BHI(tm2[rr].y));
                a4 = fmaf(2.f, a4, -BLO(tm2[rr].z));  a5 = fmaf(2.f, a5, -BHI(tm2[rr].z));
                a6 = fmaf(2.f, a6, -BLO(tm2[rr].w));  a7 = fmaf(2.f, a7, -BHI(tm2[rr].w));
            }
            nst[rr].x = packbf(a0, a1); nst[rr].y = packbf(a2, a3);
            nst[rr].z = packbf(a4, a5); nst[rr].w = packbf(a6, a7);
        }
        #pragma unroll
        for (int rr = 0; rr < 4; ++rr) tm2[rr] = T4[vr[rr]];   // T_{k-1} own rows
        __syncthreads();
        #pragma unroll
        for (int rr = 0; rr < 4; ++rr) T4[vr[rr]] = nst[rr];   // LDS <- T_k
        __syncthreads();
        // basis write of T_k from LDS: 8x128 B contiguous chunks per wave-instr
        uint4* bp = basis3 + ((size_t)stl << 9) * 1792 + ((k - 1) * 32 + f) * 8;
        #pragma unroll
        for (int rr = 0; rr < 4; ++rr){
            int v = t + rr * 1024;
            bp[(size_t)(v >> 3) * 1792 + (v & 7)] = T4[v];
        }
    }
}

// ---------------- k_probe: phaseB's load side only (ablation; runs once) -------
// Reads exactly phaseB's tile data (coalesced), results kept live via asm sink.
__global__ __launch_bounds__(256) void k_probe(
    const uint4* __restrict__ basis3, const uint4* __restrict__ t0t)
{
    int t = threadIdx.x;
    int tile = blockIdx.x;           // chunk 0: st_g = stl
    int stl = tile >> 9, vb = tile & 511;
    const uint4* srcT = t0t + ((size_t)(stl * 512 + vb)) * 256;
    const uint4* srcB = basis3 + ((size_t)(stl * 512 + vb)) * 1792;
    uint4 acc = srcT[t];
    #pragma unroll
    for (int it = 0; it < 7; ++it){
        uint4 q = srcB[it * 256 + t];
        acc.x ^= q.x; acc.y ^= q.y; acc.z ^= q.z; acc.w ^= q.w;
    }
    asm volatile("" :: "v"(acc.x), "v"(acc.y), "v"(acc.z), "v"(acc.w));
}

// ---------------- Phase B: projection GEMM (MFMA bf16), 128 rows/block ----------
// r6 MFMA/epilogue structure; staging from tile-major basis3 (contiguous loads);
// plain (non-nt) out stores so LLC merges partial lines.
__global__ __launch_bounds__(256, 2) void k_phaseB(
    const uint4* __restrict__ basis3, const uint4* __restrict__ t0t,
    const uint4* __restrict__ wtab, const float* __restrict__ bias,
    float* __restrict__ out, int st0)
{
    __shared__ uint4 A[4096];      // 64 KB = two 64-row subtiles; outT overlay in epilogue
    __shared__ uint4 WL[1024];     // 16 KB W
    int t = threadIdx.x;
    int tile = blockIdx.x;          // tile128: stl = tile>>8, vb2 = tile&255
    int stl = tile >> 8, vb2 = tile & 255;
    int st_g = st0 + stl;
    int lane = t & 63, w = t >> 6;

    // stage A: two contiguous 64-row tiles -> permuted LDS image
    #pragma unroll
    for (int h = 0; h < 2; ++h){
        int vb = vb2 * 2 + h;
        const uint4* srcT = t0t + ((size_t)(st_g * 512 + vb)) * 256;
        const uint4* srcB = basis3 + ((size_t)(stl * 512 + vb)) * 1792;
        uint4 q[8];
        q[0] = srcT[t];
        #pragma unroll
        for (int it = 0; it < 7; ++it) q[1 + it] = srcB[it * 256 + t];
        A[h * 2048 + bperm(t >> 3, t & 7)] = q[0];
        #pragma unroll
        for (int it = 0; it < 7; ++it){
            int g = it * 256 + t;
            A[h * 2048 + bperm(32 + (g >> 3), g & 7)] = q[1 + it];
        }
    }
    #pragma unroll
    for (int it = 0; it < 4; ++it) WL[(it << 8) + t] = wtab[(it << 8) + t];
    __syncthreads();

    unsigned ldsA = (unsigned)(size_t)(&A[0]);
    unsigned abase = ldsA + w * 16384 + (lane << 3);
    const char* wbase = (const char*)&WL[0];

    f32x4 acc00 = {0,0,0,0}, acc01 = {0,0,0,0}, acc10 = {0,0,0,0}, acc11 = {0,0,0,0};
    #pragma unroll
    for (int ki = 0; ki < 8; ++ki){
        s16x4 x0, x1, x2, x3;
        unsigned a0 = abase + (ki << 10);
        unsigned a1 = a0 + 8192;
        asm volatile("ds_read_b64_tr_b16 %0, %4\n\t"
                     "ds_read_b64_tr_b16 %1, %4 offset:512\n\t"
                     "ds_read_b64_tr_b16 %2, %5\n\t"
                     "ds_read_b64_tr_b16 %3, %5 offset:512\n\t"
                     "s_waitcnt lgkmcnt(0)"
                     : "=&v"(x0), "=&v"(x1), "=&v"(x2), "=&v"(x3)
                     : "v"(a0), "v"(a1));
        __builtin_amdgcn_sched_barrier(0);
        s16x8 af0, af1;
        af0[0]=x0[0]; af0[1]=x0[1]; af0[2]=x0[2]; af0[3]=x0[3];
        af0[4]=x1[0]; af0[5]=x1[1]; af0[6]=x1[2]; af0[7]=x1[3];
        af1[0]=x2[0]; af1[1]=x2[1]; af1[2]=x2[2]; af1[3]=x2[3];
        af1[4]=x3[0]; af1[5]=x3[1]; af1[6]=x3[2]; af1[7]=x3[3];
        s16x8 b0 = *(const s16x8*)(wbase + ((((ki * 2 + 0) << 6) + lane) << 4));
        s16x8 b1 = *(const s16x8*)(wbase + ((((ki * 2 + 1) << 6) + lane) << 4));
        acc00 = __builtin_amdgcn_mfma_f32_16x16x32_bf16(af0, b0, acc00, 0, 0, 0);
        acc01 = __builtin_amdgcn_mfma_f32_16x16x32_bf16(af0, b1, acc01, 0, 0, 0);
        acc10 = __builtin_amdgcn_mfma_f32_16x16x32_bf16(af1, b0, acc10, 0, 0, 0);
        acc11 = __builtin_amdgcn_mfma_f32_16x16x32_bf16(af1, b1, acc11, 0, 0, 0);
    }

    // stage 128x32 output tile into A region, then coalesced (non-nt) store
    __syncthreads();
    float* outT = (float*)&A[0];     // [fo][132] floats (16.9 KB)
    {
        int rl0 = w * 32 + ((lane >> 4) << 2);
        int foA = lane & 15, foB = 16 + (lane & 15);
        float2 p;
        p.x = acc00[0]; p.y = acc00[1]; *(float2*)&outT[foA*132 + rl0]      = p;
        p.x = acc00[2]; p.y = acc00[3]; *(float2*)&outT[foA*132 + rl0 + 2]  = p;
        p.x = acc01[0]; p.y = acc01[1]; *(float2*)&outT[foB*132 + rl0]      = p;
        p.x = acc01[2]; p.y = acc01[3]; *(float2*)&outT[foB*132 + rl0 + 2]  = p;
        p.x = acc10[0]; p.y = acc10[1]; *(float2*)&outT[foA*132 + rl0 + 16] = p;
        p.x = acc10[2]; p.y = acc10[3]; *(float2*)&outT[foA*132 + rl0 + 18] = p;
        p.x = acc11[0]; p.y = acc11[1]; *(float2*)&outT[foB*132 + rl0 + 16] = p;
        p.x = acc11[2]; p.y = acc11[3]; *(float2*)&outT[foB*132 + rl0 + 18] = p;
    }
    __syncthreads();
    {
        int fo = t >> 3;
        float bs = bias[fo];
        float* gb = out + (size_t)fo * V_N * S_N;
        #pragma unroll
        for (int it = 0; it < 4; ++it){
            int rl = ((t & 7) << 2) + (it << 5);
            float2 p0 = *(const float2*)&outT[fo*132 + rl];
            float2 p1 = *(const float2*)&outT[fo*132 + rl + 2];
            int r = vb2 * 128 + rl;          // row within stl
            int v = r >> 3, sl = r & 7;
            f32x4 o; o.x = p0.x + bs; o.y = p0.y + bs; o.z = p1.x + bs; o.w = p1.y + bs;
            *(f32x4*)(gb + (size_t)v * S_N + st_g * 8 + sl) = o;
        }
    }
}

// ---------------- host ----------------
extern "C" void kernel_launch(void* const* d_in, const int* in_sizes, int n_in,
                              void* d_out, int out_size, void* d_ws, size_t ws_size,
                              hipStream_t stream)
{
    const float* inp  = (const float*)d_in[0];
    const float* wgt  = (const float*)d_in[1];
    const float* bias = (const float*)d_in[2];
    const float* vals = (const float*)d_in[3];
    const int*   rows = (const int*)d_in[4];
    const int*   cols = (const int*)d_in[5];
    float* out = (float*)d_out;

    char* ws = (char*)d_ws;
    size_t o = 0;
    auto alloc = [&](size_t bytes) -> void* {
        void* p = ws + o; o = (o + bytes + 255) & ~(size_t)255; return p;
    };
    const size_t ELL_B = (size_t)64 * 67 * 64 * 4;   // 1.05 MB hard cap
    int* row_order = (int*)alloc(4096 * 4);
    int* sp        = (int*)alloc(4096 * 4);
    int* gcnt      = (int*)alloc(64 * 4);
    int* goff      = (int*)alloc(64 * 4);
    int* rcur      = (int*)alloc(4096 * 4);
    unsigned* ell  = (unsigned*)alloc(ELL_B);
    uint4* wtab    = (uint4*)alloc(8192 * 2);
    uint4* t0buf   = (uint4*)alloc((size_t)ST_TOT * 512 * 256 * 16);   // 56.6 MB
    size_t used = o;

    size_t per_st = (size_t)512 * 1792 * 16;         // 14.68 MB per s8-tile
    size_t avail = (ws_size > used) ? (ws_size - used) : 0;
    int tiles_c = (int)(avail / per_st);
    if (tiles_c > 16) tiles_c = 16;                  // {16,11} chunk pattern
    if (tiles_c < 1) tiles_c = 1;
    uint4* basis = (uint4*)alloc(per_st * tiles_c);  // chunk-local, region-reused

    hipMemsetAsync(ell, 0, ELL_B, stream);
    k_prep  <<<1, 1024, 0, stream>>>(rows, row_order, sp, gcnt, goff, rcur);
    k_fill2 <<<176, 256, 0, stream>>>(rows, cols, vals, sp, gcnt, goff, rcur, ell,
                                      wgt, (unsigned short*)wtab);
    k_pre   <<<2048, 256, 0, stream>>>(inp, t0buf);

    bool first = true;
    for (int st0 = 0; st0 < ST_TOT; st0 += tiles_c){
        int tc = ST_TOT - st0; if (tc > tiles_c) tc = tiles_c;
        k_phaseA<<<32 * tc, 1024, 0, stream>>>(row_order, goff, gcnt, ell, t0buf, basis, st0);
        if (first){
            int pgrid = tc * 512; if (pgrid > 4096) pgrid = 4096;
            k_probe<<<pgrid, 256, 0, stream>>>(basis, t0buf);   // ablation: load side only
            first = false;
        }
        k_phaseB<<<tc * 256, 256, 0, stream>>>(basis, t0buf, wtab, bias, out, st0);
    }
}

// Round 12
// 371.998 us; speedup vs baseline: 1.7140x; 1.2039x over previous
//
#include <hip/hip_runtime.h>
#include <stdint.h>

#define V_N    4096
#define NNZ_N  36864
#define S_N    216        // X*Y*Z = 6*6*6
#define ST_TOT 27         // S_N / 8
#define PLANES 256        // K * FIN
#define BPLANES 224       // basis planes per stl (k=1..7)

typedef float  f32x4 __attribute__((ext_vector_type(4)));
typedef short  s16x4 __attribute__((ext_vector_type(4)));
typedef short  s16x8 __attribute__((ext_vector_type(8)));
typedef _Float16 f16x8 __attribute__((ext_vector_type(8)));

static __device__ __forceinline__ unsigned short f2h(float f){
    union { _Float16 h; unsigned short u; } c; c.h = (_Float16)f; return c.u;
}
static __device__ __forceinline__ unsigned packh(float lo, float hi){
    unsigned r;
    asm("v_cvt_pkrtz_f16_f32 %0, %1, %2" : "=v"(r) : "v"(lo), "v"(hi));
    return r;
}
// acc(2xf16) += T_pair(2xf16) * broadcast(hi16(u))
#define PKFMA(acc, c, u) \
    asm("v_pk_fma_f16 %0, %1, %2, %0 op_sel:[0,1,0] op_sel_hi:[1,1,1]" \
        : "+v"(acc) : "v"(c), "v"(u))
// n = 2*a - tm2  (packed f16)
static __device__ __forceinline__ unsigned cheb(unsigned a, unsigned two, unsigned tm2){
    unsigned n;
    asm("v_pk_fma_f16 %0, %1, %2, %3 neg_lo:[0,0,1] neg_hi:[0,0,1]"
        : "=v"(n) : "v"(a), "v"(two), "v"(tm2));
    return n;
}

// tr_b16-staging permutation for a 64-row subtile (verified r7/r9)
static __device__ __forceinline__ int bperm(int p, int vrr){
    return ((vrr >> 2) << 10) + (((vrr >> 1) & 1) << 9)
         + ((p >> 5) << 6) + (((p >> 2) & 1) << 5) + (((p >> 3) & 3) << 3)
         + ((p & 3) << 1) + (vrr & 1);
}

// ---------------- k_prep: fused hist + degree-sort + group offsets (1 block) --------
__global__ __launch_bounds__(1024) void k_prep(
    const int* __restrict__ rows, int* __restrict__ row_order,
    int* __restrict__ sp, int* __restrict__ gcnt, int* __restrict__ goff,
    int* __restrict__ rcur)
{
    __shared__ int cnt[4096];
    __shared__ int c2[4096];
    __shared__ int dh[64];
    int t = threadIdx.x;
    #pragma unroll
    for (int i = 0; i < 4; ++i) cnt[t + i*1024] = 0;
    if (t < 64) dh[t] = 0;
    __syncthreads();
    for (int e = t; e < NNZ_N; e += 1024) atomicAdd(&cnt[rows[e]], 1);
    __syncthreads();
    #pragma unroll
    for (int i = 0; i < 4; ++i){
        int d = cnt[t + i*1024]; if (d > 63) d = 63;
        atomicAdd(&dh[d], 1);
    }
    __syncthreads();
    if (t == 0){ int s = 0; for (int i = 0; i < 64; ++i){ int x = dh[i]; dh[i] = s; s += x; } }
    __syncthreads();
    #pragma unroll
    for (int i = 0; i < 4; ++i){
        int v = t + i*1024;
        int d = cnt[v]; int db = d > 63 ? 63 : d;
        int pos = atomicAdd(&dh[db], 1);
        row_order[pos] = v; sp[v] = pos; c2[pos] = d;
    }
    #pragma unroll
    for (int i = 0; i < 4; ++i) rcur[t + i*1024] = 0;
    __syncthreads();
    if (t == 0){
        int off = 0;
        for (int g = 0; g < 64; ++g){
            int d = c2[g*64 + 63]; if (d > 64) d = 64;
            gcnt[g] = d; goff[g] = off; off += (d + 3) * 64;
        }
    }
}

// ---------------- k_fill2: ELL fill (blocks 0..143) + W pack (blocks 144..175) ------
__global__ void k_fill2(const int* __restrict__ rows, const int* __restrict__ cols,
                        const float* __restrict__ vals, const int* __restrict__ sp,
                        const int* __restrict__ gcnt, const int* __restrict__ goff,
                        int* __restrict__ rcur, unsigned* __restrict__ ell,
                        const float* __restrict__ w, unsigned short* __restrict__ wtab)
{
    int bid = blockIdx.x, t = threadIdx.x;
    if (bid < 144){
        int e = bid * 256 + t;
        if (e < NNZ_N){
            int r = rows[e]; int s = sp[r]; int g = s >> 6; int l = s & 63;
            int i = atomicAdd(&rcur[r], 1);
            if (i < gcnt[g])
                ell[goff[g] + i * 64 + l] =
                    ((unsigned)cols[e] << 4) | ((unsigned)f2h(vals[e]) << 16);
        }
    } else {
        int idx = (bid - 144) * 256 + t;   // 0..8191
        int slot = idx >> 3, j = idx & 7;
        int ki = slot >> 7, nh = (slot >> 6) & 1, l = slot & 63;
        int p  = ki * 32 + ((l >> 4) << 3) + j;
        int fo = nh * 16 + (l & 15);
        wtab[idx] = f2h(w[p * 32 + fo]);
    }
}

// ---------------- k_pre: input transpose -> t0 tiles (fp16) ----------------
// t0t layout: t0t[(st*512 + vb)*256 + f*8 + vrr]  (4 KB contiguous per (st,vb) tile)
__global__ __launch_bounds__(256, 4) void k_pre(
    const float* __restrict__ in, uint4* __restrict__ t0t)
{
    __shared__ unsigned short lds[64 * 218];   // 27.3 KB, row stride 436 B
    int bid = blockIdx.x;
    int f = bid >> 6, vblk = bid & 63;
    int t = threadIdx.x;
    const f32x4* src = (const f32x4*)(in + ((size_t)f * V_N + vblk * 64) * S_N);

    #pragma unroll
    for (int it = 0; it < 14; ++it){
        int idx = t + it * 256;                 // float4 index, 0..3455
        if (idx < 3456){
            int vloc = (int)(((unsigned)idx * 4855u) >> 18);   // idx / 54
            int s4   = idx - vloc * 54;
            f32x4 a = __builtin_nontemporal_load(&src[idx]);
            uint2 q; q.x = packh(a.x, a.y); q.y = packh(a.z, a.w);
            *(uint2*)((char*)lds + vloc * 436 + s4 * 8) = q;
        }
    }
    __syncthreads();
    #pragma unroll
    for (int it = 0; it < 7; ++it){
        int idx = t + it * 256;
        if (idx < ST_TOT * 64){
            int stl = idx >> 6, vl = idx & 63;
            uint4 q = *(const uint4*)((const char*)lds + vl * 436 + stl * 16);
            t0t[((size_t)(stl * 512 + vblk * 8 + (vl >> 3))) * 256 + f * 8 + (vl & 7)] = q;
        }
    }
}

// ---------------- Phase A: LDS-resident Chebyshev recurrence (packed fp16) ------
// basis3 (chunk-local): basis3[(stl*512 + vb)*1792 + ((k-1)*32+f)*8 + vrr]
__global__ __launch_bounds__(1024, 8) void k_phaseA(
    const int* __restrict__ row_order,
    const int* __restrict__ goff, const int* __restrict__ gcnt,
    const unsigned* __restrict__ ell, const uint4* __restrict__ t0t,
    uint4* __restrict__ basis3, int st0)
{
    __shared__ uint4 T4[V_N];        // 64 KB
    int f   = blockIdx.x & 31;
    int stl = blockIdx.x >> 5;       // chunk-local
    int st_g = st0 + stl;            // global
    int t = threadIdx.x;
    unsigned two = 0x40004000u;      // packed fp16 {2.0, 2.0}

    // T0 from t0t (8x128 B chunks per wave-instr)
    const uint4* t0p = t0t + ((size_t)st_g << 9) * 256 + f * 8;
    #pragma unroll
    for (int rr = 0; rr < 4; ++rr){
        int v = t + rr * 1024;
        T4[v] = t0p[(size_t)(v >> 3) * 256 + (v & 7)];
    }
    __syncthreads();

    // wave w owns groups {w, w+16, w+32, w+48}  (strided => balanced degrees)
    int w = t >> 6, lane = t & 63;
    int vr[4], gba[4], gcn[4];
    #pragma unroll
    for (int rr = 0; rr < 4; ++rr){
        int g = w + rr * 16;
        vr[rr]  = row_order[g * 64 + lane];
        gba[rr] = goff[g] + lane;
        gcn[rr] = __builtin_amdgcn_readfirstlane(gcnt[g]);
    }
    uint4 tm2[4];
    #pragma unroll
    for (int rr = 0; rr < 4; ++rr) tm2[rr] = T4[vr[rr]];   // T0 own rows

    for (int k = 1; k < 8; ++k){
        uint4 nst[4];
        #pragma unroll
        for (int rr = 0; rr < 4; ++rr){
            unsigned ac0 = 0, ac1 = 0, ac2 = 0, ac3 = 0;
            const unsigned* ep = ell + gba[rr];
            int cnt = gcn[rr];
            unsigned u0 = ep[0];
            unsigned u1 = ep[64];
            for (int i = 0; i < cnt; i += 2){
                unsigned n0 = ep[(i + 2) << 6];     // prefetch next pair (pad rows are 0)
                unsigned n1 = ep[(i + 3) << 6];
                uint4 q0 = *(const uint4*)((const char*)T4 + (u0 & 0xFFF0u));
                uint4 q1 = *(const uint4*)((const char*)T4 + (u1 & 0xFFF0u));
                PKFMA(ac0, q0.x, u0);  PKFMA(ac1, q0.y, u0);
                PKFMA(ac2, q0.z, u0);  PKFMA(ac3, q0.w, u0);
                PKFMA(ac0, q1.x, u1);  PKFMA(ac1, q1.y, u1);
                PKFMA(ac2, q1.z, u1);  PKFMA(ac3, q1.w, u1);
                u0 = n0; u1 = n1;
            }
            if (k > 1){
                nst[rr].x = cheb(ac0, two, tm2[rr].x);
                nst[rr].y = cheb(ac1, two, tm2[rr].y);
                nst[rr].z = cheb(ac2, two, tm2[rr].z);
                nst[rr].w = cheb(ac3, two, tm2[rr].w);
            } else {
                nst[rr].x = ac0; nst[rr].y = ac1; nst[rr].z = ac2; nst[rr].w = ac3;
            }
        }
        #pragma unroll
        for (int rr = 0; rr < 4; ++rr) tm2[rr] = T4[vr[rr]];   // T_{k-1} own rows
        __syncthreads();
        #pragma unroll
        for (int rr = 0; rr < 4; ++rr) T4[vr[rr]] = nst[rr];   // LDS <- T_k
        __syncthreads();
        // basis write of T_k from LDS: 8x128 B contiguous chunks per wave-instr
        uint4* bp = basis3 + ((size_t)stl << 9) * 1792 + ((k - 1) * 32 + f) * 8;
        #pragma unroll
        for (int rr = 0; rr < 4; ++rr){
            int v = t + rr * 1024;
            bp[(size_t)(v >> 3) * 1792 + (v & 7)] = T4[v];
        }
    }
}

// ---------------- Phase B: projection GEMM (MFMA f16), 128 rows/block ----------
__global__ __launch_bounds__(256, 2) void k_phaseB(
    const uint4* __restrict__ basis3, const uint4* __restrict__ t0t,
    const uint4* __restrict__ wtab, const float* __restrict__ bias,
    float* __restrict__ out, int st0)
{
    __shared__ uint4 A[4096];      // 64 KB = two 64-row subtiles; outT overlay in epilogue
    __shared__ uint4 WL[1024];     // 16 KB W
    int t = threadIdx.x;
    int tile = blockIdx.x;          // tile128: stl = tile>>8, vb2 = tile&255
    int stl = tile >> 8, vb2 = tile & 255;
    int st_g = st0 + stl;
    int lane = t & 63, w = t >> 6;

    // stage A: two contiguous 64-row tiles -> permuted LDS image
    #pragma unroll
    for (int h = 0; h < 2; ++h){
        int vb = vb2 * 2 + h;
        const uint4* srcT = t0t + ((size_t)(st_g * 512 + vb)) * 256;
        const uint4* srcB = basis3 + ((size_t)(stl * 512 + vb)) * 1792;
        uint4 q[8];
        q[0] = srcT[t];
        #pragma unroll
        for (int it = 0; it < 7; ++it) q[1 + it] = srcB[it * 256 + t];
        A[h * 2048 + bperm(t >> 3, t & 7)] = q[0];
        #pragma unroll
        for (int it = 0; it < 7; ++it){
            int g = it * 256 + t;
            A[h * 2048 + bperm(32 + (g >> 3), g & 7)] = q[1 + it];
        }
    }
    #pragma unroll
    for (int it = 0; it < 4; ++it) WL[(it << 8) + t] = wtab[(it << 8) + t];
    __syncthreads();

    unsigned ldsA = (unsigned)(size_t)(&A[0]);
    unsigned abase = ldsA + w * 16384 + (lane << 3);
    const char* wbase = (const char*)&WL[0];

    f32x4 acc00 = {0,0,0,0}, acc01 = {0,0,0,0}, acc10 = {0,0,0,0}, acc11 = {0,0,0,0};
    #pragma unroll
    for (int ki = 0; ki < 8; ++ki){
        s16x4 x0, x1, x2, x3;
        unsigned a0 = abase + (ki << 10);
        unsigned a1 = a0 + 8192;
        asm volatile("ds_read_b64_tr_b16 %0, %4\n\t"
                     "ds_read_b64_tr_b16 %1, %4 offset:512\n\t"
                     "ds_read_b64_tr_b16 %2, %5\n\t"
                     "ds_read_b64_tr_b16 %3, %5 offset:512\n\t"
                     "s_waitcnt lgkmcnt(0)"
                     : "=&v"(x0), "=&v"(x1), "=&v"(x2), "=&v"(x3)
                     : "v"(a0), "v"(a1));
        __builtin_amdgcn_sched_barrier(0);
        s16x8 af0, af1;
        af0[0]=x0[0]; af0[1]=x0[1]; af0[2]=x0[2]; af0[3]=x0[3];
        af0[4]=x1[0]; af0[5]=x1[1]; af0[6]=x1[2]; af0[7]=x1[3];
        af1[0]=x2[0]; af1[1]=x2[1]; af1[2]=x2[2]; af1[3]=x2[3];
        af1[4]=x3[0]; af1[5]=x3[1]; af1[6]=x3[2]; af1[7]=x3[3];
        s16x8 b0 = *(const s16x8*)(wbase + ((((ki * 2 + 0) << 6) + lane) << 4));
        s16x8 b1 = *(const s16x8*)(wbase + ((((ki * 2 + 1) << 6) + lane) << 4));
        acc00 = __builtin_amdgcn_mfma_f32_16x16x32_f16(*(const f16x8*)&af0, *(const f16x8*)&b0, acc00, 0, 0, 0);
        acc01 = __builtin_amdgcn_mfma_f32_16x16x32_f16(*(const f16x8*)&af0, *(const f16x8*)&b1, acc01, 0, 0, 0);
        acc10 = __builtin_amdgcn_mfma_f32_16x16x32_f16(*(const f16x8*)&af1, *(const f16x8*)&b0, acc10, 0, 0, 0);
        acc11 = __builtin_amdgcn_mfma_f32_16x16x32_f16(*(const f16x8*)&af1, *(const f16x8*)&b1, acc11, 0, 0, 0);
    }

    // stage 128x32 output tile into A region, then coalesced (non-nt) store
    __syncthreads();
    float* outT = (float*)&A[0];     // [fo][132] floats (16.9 KB)
    {
        int rl0 = w * 32 + ((lane >> 4) << 2);
        int foA = lane & 15, foB = 16 + (lane & 15);
        float2 p;
        p.x = acc00[0]; p.y = acc00[1]; *(float2*)&outT[foA*132 + rl0]      = p;
        p.x = acc00[2]; p.y = acc00[3]; *(float2*)&outT[foA*132 + rl0 + 2]  = p;
        p.x = acc01[0]; p.y = acc01[1]; *(float2*)&outT[foB*132 + rl0]      = p;
        p.x = acc01[2]; p.y = acc01[3]; *(float2*)&outT[foB*132 + rl0 + 2]  = p;
        p.x = acc10[0]; p.y = acc10[1]; *(float2*)&outT[foA*132 + rl0 + 16] = p;
        p.x = acc10[2]; p.y = acc10[3]; *(float2*)&outT[foA*132 + rl0 + 18] = p;
        p.x = acc11[0]; p.y = acc11[1]; *(float2*)&outT[foB*132 + rl0 + 16] = p;
        p.x = acc11[2]; p.y = acc11[3]; *(float2*)&outT[foB*132 + rl0 + 18] = p;
    }
    __syncthreads();
    {
        int fo = t >> 3;
        float bs = bias[fo];
        float* gb = out + (size_t)fo * V_N * S_N;
        #pragma unroll
        for (int it = 0; it < 4; ++it){
            int rl = ((t & 7) << 2) + (it << 5);
            float2 p0 = *(const float2*)&outT[fo*132 + rl];
            float2 p1 = *(const float2*)&outT[fo*132 + rl + 2];
            int r = vb2 * 128 + rl;          // row within stl
            int v = r >> 3, sl = r & 7;
            f32x4 o; o.x = p0.x + bs; o.y = p0.y + bs; o.z = p1.x + bs; o.w = p1.y + bs;
            *(f32x4*)(gb + (size_t)v * S_N + st_g * 8 + sl) = o;
        }
    }
}

// ---------------- host ----------------
extern "C" void kernel_launch(void* const* d_in, const int* in_sizes, int n_in,
                              void* d_out, int out_size, void* d_ws, size_t ws_size,
                              hipStream_t stream)
{
    const float* inp  = (const float*)d_in[0];
    const float* wgt  = (const float*)d_in[1];
    const float* bias = (const float*)d_in[2];
    const float* vals = (const float*)d_in[3];
    const int*   rows = (const int*)d_in[4];
    const int*   cols = (const int*)d_in[5];
    float* out = (float*)d_out;

    char* ws = (char*)d_ws;
    size_t o = 0;
    auto alloc = [&](size_t bytes) -> void* {
        void* p = ws + o; o = (o + bytes + 255) & ~(size_t)255; return p;
    };
    const size_t ELL_B = (size_t)64 * 67 * 64 * 4;   // 1.05 MB hard cap
    int* row_order = (int*)alloc(4096 * 4);
    int* sp        = (int*)alloc(4096 * 4);
    int* gcnt      = (int*)alloc(64 * 4);
    int* goff      = (int*)alloc(64 * 4);
    int* rcur      = (int*)alloc(4096 * 4);
    unsigned* ell  = (unsigned*)alloc(ELL_B);
    uint4* wtab    = (uint4*)alloc(8192 * 2);
    uint4* t0buf   = (uint4*)alloc((size_t)ST_TOT * 512 * 256 * 16);   // 56.6 MB
    size_t used = o;

    size_t per_st = (size_t)512 * 1792 * 16;         // 14.68 MB per s8-tile
    size_t avail = (ws_size > used) ? (ws_size - used) : 0;
    int tiles_c = (int)(avail / per_st);
    if (tiles_c > 16) tiles_c = 16;                  // {16,11} chunk pattern
    if (tiles_c < 1) tiles_c = 1;
    uint4* basis = (uint4*)alloc(per_st * tiles_c);  // chunk-local, region-reused

    hipMemsetAsync(ell, 0, ELL_B, stream);
    k_prep  <<<1, 1024, 0, stream>>>(rows, row_order, sp, gcnt, goff, rcur);
    k_fill2 <<<176, 256, 0, stream>>>(rows, cols, vals, sp, gcnt, goff, rcur, ell,
                                      wgt, (unsigned short*)wtab);
    k_pre   <<<2048, 256, 0, stream>>>(inp, t0buf);

    for (int st0 = 0; st0 < ST_TOT; st0 += tiles_c){
        int tc = ST_TOT - st0; if (tc > tiles_c) tc = tiles_c;
        k_phaseA<<<32 * tc, 1024, 0, stream>>>(row_order, goff, gcnt, ell, t0buf, basis, st0);
        k_phaseB<<<tc * 256, 256, 0, stream>>>(basis, t0buf, wtab, bias, out, st0);
    }
}